// Round 24
// baseline (1603.662 us; speedup 1.0000x reference)
//
#include <hip/hip_runtime.h>
#include <math.h>

#define B_  4
#define L_  512
#define D_  512
#define DIN 1024
#define DST 16
#define DCV 4
#define DTR 32
#define NL  3
#define H2  256
#define LCH 64    // scan chunk length (8 chunks)
#define WSC 0.28f // lstm i8 weight scale

typedef _Float16 __f16;
typedef __f16 f16x2 __attribute__((ext_vector_type(2)));
typedef __f16 half8 __attribute__((ext_vector_type(8)));
typedef float f32x4v __attribute__((ext_vector_type(4)));
typedef unsigned uint4v __attribute__((ext_vector_type(4)));

__device__ __forceinline__ float fast_sigmoid(float x) { return 1.f / (1.f + __expf(-x)); }
__device__ __forceinline__ float fast_tanh(float x) { return 2.f / (1.f + __expf(-2.f * x)) - 1.f; }

__device__ __forceinline__ unsigned packf16(float a, float b) {
  f16x2 p; p.x = (__f16)a; p.y = (__f16)b;
  return __builtin_bit_cast(unsigned, p);
}
__device__ __forceinline__ int sdot4(unsigned a, unsigned b, int c) {
  return __builtin_amdgcn_sdot4((int)a, (int)b, c, false);
}
__device__ __forceinline__ int q8(float v) {
  float c = fmaxf(fminf(v, 127.f), -127.f);
  return (int)rintf(c);
}

// ---------------- LSTM segment (device fn; runs on 8 piggyback blocks) ----------------
// Steps [s0,s1). State (c per thread, h8 buffer) persists in global between dispatches.
__device__ void lstm_seg(char* smem, const __f16* gxh, const uint4* wpk8,
                         __f16* comb, float* c_state, uint4* h8_state,
                         int s0, int s1, int lb)
{
  uint4* wg_lds = (uint4*)smem;            // 8*512 uint4 = 64KB (g gate i8)
  uint4* wo_lds = wg_lds + 8 * 512;        // 64KB (o gate i8)
  uint4* h8s    = wo_lds + 8 * 512;        // [2][16] uint4 ping-pong
  const int dir = lb >> 2, b = lb & 3;
  const int t = threadIdx.x;
  const int j = t >> 1, ks = t & 1;
  const uint4* wp8 = wpk8 + (size_t)dir * 4 * 8 * 512;
  const float WS = WSC / (127.f * 127.f);

  #pragma unroll
  for (int q = 0; q < 8; ++q) {
    wg_lds[q * 512 + t] = wp8[(2 * 8 + q) * 512 + t];
    wo_lds[q * 512 + t] = wp8[(3 * 8 + q) * 512 + t];
  }
  int buf = s0 & 1;
  if (s0 == 0) {
    if (t < 128) ((unsigned*)h8s)[t] = 0u;
  } else {
    if (t < 64) ((unsigned*)h8s)[buf * 64 + t] = ((const unsigned*)(h8_state + lb * 16))[t];
  }
  float c_reg = (s0 == 0) ? 0.f : c_state[lb * 512 + t];
  __f16* outp = comb + 512 + dir * 256;
  const __f16* gxb = gxh + (size_t)(b * L_) * 2048 + dir * 1024;
  const int offA = (ks ? 1 : 0) * 256 + j;   // ks0 -> gate i, ks1 -> gate f
  const int offB = (ks ? 3 : 2) * 256 + j;   // ks0 -> gate g, ks1 -> gate o
  const int d_   = t >> 3;
  const int ks8  = d_ >> 5;
  const int h8i  = (((d_ - ks8 * 32) >> 2) * 2 + ks8) * 4 + (d_ & 3);
  __syncthreads();

  const int l00 = dir ? (L_ - 1 - s0) : s0;
  float pgA = (float)gxb[(size_t)l00 * 2048 + offA];
  float pgB = (float)gxb[(size_t)l00 * 2048 + offB];

#define W8STEP(q) { \
    uint4 hq = h8s[buf * 16 + (q) * 2 + ks]; \
    uint4 wi_ = wp8[(0*8+(q))*512 + t]; \
    uint4 wf_ = wp8[(1*8+(q))*512 + t]; \
    uint4 wg = wg_lds[(q)*512 + t]; \
    uint4 wo = wo_lds[(q)*512 + t]; \
    ii_ = sdot4(wi_.x, hq.x, ii_); ii_ = sdot4(wi_.y, hq.y, ii_); \
    ii_ = sdot4(wi_.z, hq.z, ii_); ii_ = sdot4(wi_.w, hq.w, ii_); \
    if_ = sdot4(wf_.x, hq.x, if_); if_ = sdot4(wf_.y, hq.y, if_); \
    if_ = sdot4(wf_.z, hq.z, if_); if_ = sdot4(wf_.w, hq.w, if_); \
    ig_ = sdot4(wg.x, hq.x, ig_); ig_ = sdot4(wg.y, hq.y, ig_); \
    ig_ = sdot4(wg.z, hq.z, ig_); ig_ = sdot4(wg.w, hq.w, ig_); \
    io_ = sdot4(wo.x, hq.x, io_); io_ = sdot4(wo.y, hq.y, io_); \
    io_ = sdot4(wo.z, hq.z, io_); io_ = sdot4(wo.w, hq.w, io_); }

  for (int s = s0; s < s1; ++s) {
    const int l = dir ? (L_ - 1 - s) : s;
    float pgA_n = 0.f, pgB_n = 0.f;
    if (s + 1 < L_) {
      const int ln = dir ? (L_ - 2 - s) : (s + 1);
      pgA_n = (float)gxb[(size_t)ln * 2048 + offA];
      pgB_n = (float)gxb[(size_t)ln * 2048 + offB];
    }
    int ii_ = 0, if_ = 0, ig_ = 0, io_ = 0;
    W8STEP(0) W8STEP(1) W8STEP(2) W8STEP(3)
    W8STEP(4) W8STEP(5) W8STEP(6) W8STEP(7)
    float a0 = (float)ii_ * WS;
    float a1 = (float)if_ * WS;
    float a2 = (float)ig_ * WS;
    float a3 = (float)io_ * WS;
    if (ks == 0) { a0 += pgA; a2 += pgB; } else { a1 += pgA; a3 += pgB; }
    a0 += __shfl_xor(a0, 1, 64);
    a1 += __shfl_xor(a1, 1, 64);
    a2 += __shfl_xor(a2, 1, 64);
    a3 += __shfl_xor(a3, 1, 64);
    const float si = fast_sigmoid(a0);
    const float sf = fast_sigmoid(a1);
    const float tg = fast_tanh(a2);
    const float so = fast_sigmoid(a3);
    c_reg = fmaf(sf, c_reg, si * tg);
    const float hv = so * fast_tanh(c_reg);
    if (ks == 0) outp[(size_t)(b * L_ + l) * 1024 + j] = (__f16)hv;
    const float hv1 = __shfl_xor(hv, 2, 64);
    const float hv2 = __shfl_xor(hv, 4, 64);
    const float hv3 = __shfl_xor(hv1, 4, 64);
    if ((t & 7) == 0) {
      int q0 = (int)rintf(hv  * 127.f), q1 = (int)rintf(hv1 * 127.f);
      int q2 = (int)rintf(hv2 * 127.f), q3 = (int)rintf(hv3 * 127.f);
      ((unsigned*)(h8s + (buf ^ 1) * 16))[h8i] =
          (unsigned)(q0 & 255) | ((unsigned)(q1 & 255) << 8) |
          ((unsigned)(q2 & 255) << 16) | ((unsigned)(q3 & 255) << 24);
    }
    pgA = pgA_n; pgB = pgB_n;
    buf ^= 1;
    __syncthreads();
  }
#undef W8STEP
  // persist state
  if (t < 64) ((unsigned*)(h8_state + lb * 16))[t] = ((unsigned*)(h8s + (s1 & 1) * 16))[t];
  c_state[lb * 512 + t] = c_reg;
}

// ---------------- 512-thr 2-tile f16 MFMA GEMM with optional LSTM piggyback ----------------
template<int ACT, bool HOUT>
__global__ __launch_bounds__(512, 1) void gemm512(
    const __f16* __restrict__ A, const __f16* __restrict__ W, void* __restrict__ Cv,
    int nx, int M, int N, int K, int lda, int ldb, int ldc,
    const float* __restrict__ bias,
    int tileBlocks,
    const __f16* __restrict__ gxh, const uint4* __restrict__ wpk8,
    __f16* __restrict__ comb, float* __restrict__ c_state, uint4* __restrict__ h8_state,
    int s0, int s1)
{
  extern __shared__ char smem[];
  if ((int)blockIdx.x >= tileBlocks) {
    lstm_seg(smem, gxh, wpk8, comb, c_state, h8_state, s0, s1, (int)blockIdx.x - tileBlocks);
    return;
  }
  const int half = threadIdx.x >> 8;
  const int tid  = threadIdx.x & 255;
  const int tile = (int)blockIdx.x * 2 + half;
  const int tx = tile % nx, ty = tile / nx;
  uint4v* As = (uint4v*)(smem + half * 32768);
  uint4v* Bs = As + 1024;
  const int lane = tid & 63, wid = tid >> 6;
  const int wr = wid >> 1, wc = wid & 1;
  const int fr = lane & 15, fq = lane >> 4;
  const int m0 = ty * 128, n0 = tx * 128;
  const int srow = tid >> 3, skb = tid & 7;

  f32x4v acc[4][4] = {};
  for (int k0 = 0; k0 < K; k0 += 64) {
    const __f16* Ab = A + (size_t)m0 * lda + k0;
    const __f16* Bb = W + (size_t)n0 * ldb + k0;
    #pragma unroll
    for (int i = 0; i < 4; ++i) {
      int row = srow + i * 32;
      uint4v ap = *(const uint4v*)(Ab + (size_t)row * lda + skb * 8);
      uint4v bp = *(const uint4v*)(Bb + (size_t)row * ldb + skb * 8);
      As[row * 8 + (skb ^ (row & 7))] = ap;
      Bs[row * 8 + (skb ^ (row & 7))] = bp;
    }
    __syncthreads();
    #pragma unroll
    for (int ks = 0; ks < 2; ++ks) {
      half8 af[4], bf[4];
      #pragma unroll
      for (int mt = 0; mt < 4; ++mt) {
        int row = wr * 64 + mt * 16 + fr;
        int kb = ks * 4 + fq;
        af[mt] = __builtin_bit_cast(half8, As[row * 8 + (kb ^ (row & 7))]);
      }
      #pragma unroll
      for (int nt = 0; nt < 4; ++nt) {
        int row = wc * 64 + nt * 16 + fr;
        int kb = ks * 4 + fq;
        bf[nt] = __builtin_bit_cast(half8, Bs[row * 8 + (kb ^ (row & 7))]);
      }
      #pragma unroll
      for (int mt = 0; mt < 4; ++mt)
        #pragma unroll
        for (int nt = 0; nt < 4; ++nt)
          acc[mt][nt] = __builtin_amdgcn_mfma_f32_16x16x32_f16(af[mt], bf[nt], acc[mt][nt], 0, 0, 0);
    }
    __syncthreads();
  }
  float* C = (float*)Cv;
  __f16* Ch = (__f16*)Cv;
  #pragma unroll
  for (int nt = 0; nt < 4; ++nt) {
    int n = n0 + wc * 64 + nt * 16 + fr;
    float bv = bias ? bias[n] : 0.f;
    #pragma unroll
    for (int mt = 0; mt < 4; ++mt) {
      #pragma unroll
      for (int r = 0; r < 4; ++r) {
        int m = m0 + wr * 64 + mt * 16 + fq * 4 + r;
        float v = acc[mt][nt][r] + bv;
        if (ACT == 1) v = (v > 20.f) ? v : log1pf(__expf(v));
        if (HOUT) Ch[(size_t)m * ldc + n] = (__f16)v;
        else C[(size_t)m * ldc + n] = v;
      }
    }
  }
}

// ---------------- 256-thr f16 MFMA GEMM (gx + fusion; unhosted) ----------------
template<int ACT, bool HOUT>
__global__ __launch_bounds__(256) void gemm_mfma_h(
    const __f16* __restrict__ A, const __f16* __restrict__ W, void* __restrict__ Cv,
    int M, int N, int K, int lda, int ldb, int ldc,
    const float* __restrict__ bias, const float* __restrict__ bias2)
{
  __shared__ uint4v As[1024];
  __shared__ uint4v Bs[1024];
  const int tid  = threadIdx.x;
  const int lane = tid & 63, wid = tid >> 6;
  const int wr = wid >> 1, wc = wid & 1;
  const int fr = lane & 15, fq = lane >> 4;
  const int m0 = blockIdx.y * 128, n0 = blockIdx.x * 128;
  const int srow = tid >> 3, skb = tid & 7;

  f32x4v acc[4][4] = {};
  for (int k0 = 0; k0 < K; k0 += 64) {
    const __f16* Ab = A + (size_t)m0 * lda + k0;
    const __f16* Bb = W + (size_t)n0 * ldb + k0;
    #pragma unroll
    for (int i = 0; i < 4; ++i) {
      int row = srow + i * 32;
      uint4v ap = *(const uint4v*)(Ab + (size_t)row * lda + skb * 8);
      uint4v bp = *(const uint4v*)(Bb + (size_t)row * ldb + skb * 8);
      As[row * 8 + (skb ^ (row & 7))] = ap;
      Bs[row * 8 + (skb ^ (row & 7))] = bp;
    }
    __syncthreads();
    #pragma unroll
    for (int ks = 0; ks < 2; ++ks) {
      half8 af[4], bf[4];
      #pragma unroll
      for (int mt = 0; mt < 4; ++mt) {
        int row = wr * 64 + mt * 16 + fr;
        int kb = ks * 4 + fq;
        af[mt] = __builtin_bit_cast(half8, As[row * 8 + (kb ^ (row & 7))]);
      }
      #pragma unroll
      for (int nt = 0; nt < 4; ++nt) {
        int row = wc * 64 + nt * 16 + fr;
        int kb = ks * 4 + fq;
        bf[nt] = __builtin_bit_cast(half8, Bs[row * 8 + (kb ^ (row & 7))]);
      }
      #pragma unroll
      for (int mt = 0; mt < 4; ++mt)
        #pragma unroll
        for (int nt = 0; nt < 4; ++nt)
          acc[mt][nt] = __builtin_amdgcn_mfma_f32_16x16x32_f16(af[mt], bf[nt], acc[mt][nt], 0, 0, 0);
    }
    __syncthreads();
  }
  float* C = (float*)Cv;
  __f16* Ch = (__f16*)Cv;
  #pragma unroll
  for (int nt = 0; nt < 4; ++nt) {
    int n = n0 + wc * 64 + nt * 16 + fr;
    float bv = (bias ? bias[n] : 0.f) + (bias2 ? bias2[n] : 0.f);
    #pragma unroll
    for (int mt = 0; mt < 4; ++mt) {
      #pragma unroll
      for (int r = 0; r < 4; ++r) {
        int m = m0 + wr * 64 + mt * 16 + fq * 4 + r;
        float v = acc[mt][nt][r] + bv;
        if (ACT == 1) v = (v > 20.f) ? v : log1pf(__expf(v));
        if (HOUT) Ch[(size_t)m * ldc + n] = (__f16)v;
        else C[(size_t)m * ldc + n] = v;
      }
    }
  }
}

// generic f32 -> f16 pack
__global__ __launch_bounds__(256) void packh(
    const float* __restrict__ src, __f16* __restrict__ dst, int n)
{
  int t = blockIdx.x * 256 + threadIdx.x;
  if (t < n) dst[t] = (__f16)src[t];
}

__global__ __launch_bounds__(256) void pack_xpw_h(
    const float* __restrict__ xpw, __f16* __restrict__ dst)
{
  int t = blockIdx.x * 256 + threadIdx.x;
  int layer = t >> 17;
  int r = (t >> 10) & 127;
  int k = t & 1023;
  dst[t] = (r < 64) ? (__f16)xpw[layer * 65536 + r * 1024 + k] : (__f16)0.f;
}

__global__ __launch_bounds__(256) void pack_dwh(
    const float* __restrict__ dw, __f16* __restrict__ dst)
{
  int t = blockIdx.x * 256 + threadIdx.x;
  int layer = t >> 16;
  int r = (t >> 6) & 1023;
  int k = t & 63;
  dst[t] = (k < 32) ? (__f16)dw[layer * 32768 + r * 32 + k] : (__f16)0.f;
}

__global__ __launch_bounds__(256) void pack_whh_i8(
    const float* __restrict__ whh, uint4* __restrict__ dst)
{
  int idx = blockIdx.x * 256 + threadIdx.x;
  int t = idx & 511;
  int q = (idx >> 9) & 7;
  int r = idx >> 12;
  int G = r & 3, dir = r >> 2;
  int j = t >> 1, ks = t & 1;
  const float* src = whh + (size_t)dir * 262144 + (size_t)(G * 256 + j) * 256 + ks * 128 + q * 16;
  const float inv = 127.f / WSC;
  unsigned d[4];
  #pragma unroll
  for (int w = 0; w < 4; ++w) {
    float4 f = ((const float4*)src)[w];
    int q0 = q8(f.x * inv), q1 = q8(f.y * inv), q2 = q8(f.z * inv), q3 = q8(f.w * inv);
    d[w] = (unsigned)(q0 & 255) | ((unsigned)(q1 & 255) << 8) |
           ((unsigned)(q2 & 255) << 16) | ((unsigned)(q3 & 255) << 24);
  }
  uint4 pk; pk.x = d[0]; pk.y = d[1]; pk.z = d[2]; pk.w = d[3];
  dst[idx] = pk;
}

// u[b,l,c] = silu(cb[c] + conv(xin)); f16 out only
__global__ __launch_bounds__(256) void conv_silu(
    const float* __restrict__ xz, const float* __restrict__ cw, const float* __restrict__ cb,
    __f16* __restrict__ uh)
{
  int t = blockIdx.x * 256 + threadIdx.x;
  int c  = t & (DIN - 1);
  int bl = t >> 10;
  int l  = bl & (L_ - 1);
  float acc = cb[c];
  #pragma unroll
  for (int k = 0; k < DCV; ++k) {
    int ls = l + k - (DCV - 1);
    if (ls >= 0)
      acc = fmaf(xz[(size_t)(bl + k - (DCV - 1)) * 2048 + c], cw[c * DCV + k], acc);
  }
  float v = acc * fast_sigmoid(acc);
  uh[t] = (__f16)v;
}

// ---------------- chunked selective scan (2-pass, exact by linearity) ----------------
__global__ __launch_bounds__(256) void scan_part(
    const float* __restrict__ dt, const __f16* __restrict__ uh,
    const __f16* __restrict__ xdh, const float* __restrict__ A_log,
    float* __restrict__ hend, float* __restrict__ Pp)
{
  int t = blockIdx.x * 256 + threadIdx.x;
  int n  = t & 15;
  int ch = (t >> 4) & 7;
  int bc = t >> 7;
  int c  = bc & (DIN - 1);
  int b  = bc >> 10;
  float Ac = -__expf(A_log[c * DST + n]);
  float h = 0.f, P = 1.f;
  const size_t row = (size_t)b * L_ + ch * LCH;

#define DECLP(i) float dtv##i, uv##i, Bn##i;
  DECLP(0) DECLP(1) DECLP(2) DECLP(3)
#define LOADP(i, l) { \
    const size_t nb_ = row + (l); \
    dtv##i = dt[nb_ * DIN + c]; \
    uv##i  = (float)uh[nb_ * DIN + c]; \
    Bn##i  = (float)xdh[nb_ * 128 + 32 + n]; }
#define STEPP(i) { \
    float dA_ = __expf(dtv##i * Ac); \
    h = fmaf(dA_, h, (dtv##i * uv##i) * Bn##i); \
    P *= dA_; }

  LOADP(0, 0) LOADP(1, 1) LOADP(2, 2) LOADP(3, 3)
  for (int l = 0; l < LCH - 4; l += 4) {
    STEPP(0) LOADP(0, l + 4)
    STEPP(1) LOADP(1, l + 5)
    STEPP(2) LOADP(2, l + 6)
    STEPP(3) LOADP(3, l + 7)
  }
  STEPP(0) STEPP(1) STEPP(2) STEPP(3)
#undef DECLP
#undef LOADP
#undef STEPP
  int flat = bc * 16 + n;
  hend[ch * 65536 + flat] = h;
  Pp[ch * 65536 + flat]   = P;
}

__global__ __launch_bounds__(256) void scan_fix(
    const float* __restrict__ dt, const __f16* __restrict__ uh,
    const __f16* __restrict__ xdh, const float* __restrict__ xz,
    const float* __restrict__ A_log, const float* __restrict__ Dp,
    const float* __restrict__ hend, const float* __restrict__ Pp,
    __f16* __restrict__ y)
{
  int t = blockIdx.x * 256 + threadIdx.x;
  int n  = t & 15;
  int ch = (t >> 4) & 7;
  int bc = t >> 7;
  int c  = bc & (DIN - 1);
  int b  = bc >> 10;
  float Ac = -__expf(A_log[c * DST + n]);
  float Dc = Dp[c];
  const int flat = bc * 16 + n;
  float h = 0.f;
  for (int c2 = 0; c2 < ch; ++c2)
    h = fmaf(Pp[c2 * 65536 + flat], h, hend[c2 * 65536 + flat]);
  const size_t row = (size_t)b * L_ + ch * LCH;

#define DECLP(i) float dtv##i, uv##i, Bn##i, Cn##i, zv##i;
  DECLP(0) DECLP(1) DECLP(2) DECLP(3)
#define LOADP(i, l) { \
    const size_t nb_ = row + (l); \
    dtv##i = dt[nb_ * DIN + c]; \
    uv##i  = (float)uh[nb_ * DIN + c]; \
    Bn##i  = (float)xdh[nb_ * 128 + 32 + n]; \
    Cn##i  = (float)xdh[nb_ * 128 + 48 + n]; \
    zv##i  = xz[nb_ * 2048 + 1024 + c]; }
#define STEPP(i, l) { \
    float dA_ = __expf(dtv##i * Ac); \
    h = fmaf(dA_, h, (dtv##i * uv##i) * Bn##i); \
    float p_ = h * Cn##i; \
    p_ += __shfl_xor(p_, 1, 64); \
    p_ += __shfl_xor(p_, 2, 64); \
    p_ += __shfl_xor(p_, 4, 64); \
    p_ += __shfl_xor(p_, 8, 64); \
    if (n == 0) { \
      float yv_ = p_ + uv##i * Dc; \
      yv_ *= zv##i * fast_sigmoid(zv##i); \
      y[(row + (l)) * DIN + c] = (__f16)yv_; \
    } }

  LOADP(0, 0) LOADP(1, 1) LOADP(2, 2) LOADP(3, 3)
  for (int l = 0; l < LCH - 4; l += 4) {
    STEPP(0, l)     LOADP(0, l + 4)
    STEPP(1, l + 1) LOADP(1, l + 5)
    STEPP(2, l + 2) LOADP(2, l + 6)
    STEPP(3, l + 3) LOADP(3, l + 7)
  }
  STEPP(0, LCH - 4) STEPP(1, LCH - 3) STEPP(2, LCH - 2) STEPP(3, LCH - 1)
#undef DECLP
#undef LOADP
#undef STEPP
}

// layernorm(a + mo)*g + b -> optional f32 out + f16 out
__global__ __launch_bounds__(64) void resid_ln(
    const float* __restrict__ a, const float* __restrict__ mo,
    const float* __restrict__ g, const float* __restrict__ bta,
    float* __restrict__ outm, int ldo, __f16* __restrict__ outh, int ldoh)
{
  int row = blockIdx.x;
  int lane = threadIdx.x;
  const float* pa = a  + (size_t)row * 512;
  const float* pb = mo + (size_t)row * 512;
  float v[8];
  float s = 0.f, s2 = 0.f;
  #pragma unroll
  for (int i = 0; i < 8; ++i) {
    float x = pa[lane + i * 64] + pb[lane + i * 64];
    v[i] = x; s += x; s2 += x * x;
  }
  #pragma unroll
  for (int off = 1; off < 64; off <<= 1) {
    s  += __shfl_xor(s,  off, 64);
    s2 += __shfl_xor(s2, off, 64);
  }
  float mean = s * (1.f / 512.f);
  float var  = s2 * (1.f / 512.f) - mean * mean;
  float rstd = rsqrtf(var + 1e-5f);
  #pragma unroll
  for (int i = 0; i < 8; ++i) {
    int cidx = lane + i * 64;
    float o = (v[i] - mean) * rstd * g[cidx] + bta[cidx];
    if (outm) outm[(size_t)row * ldo + cidx] = o;
    outh[(size_t)row * ldoh + cidx] = (__f16)o;
  }
}

extern "C" void kernel_launch(void* const* d_in, const int* in_sizes, int n_in,
                              void* d_out, int out_size, void* d_ws, size_t ws_size,
                              hipStream_t stream)
{
  const float* x    = (const float*)d_in[0];
  const float* wi   = (const float*)d_in[1];
  const float* cw   = (const float*)d_in[2];
  const float* cb   = (const float*)d_in[3];
  const float* xpw  = (const float*)d_in[4];
  const float* dw   = (const float*)d_in[5];
  const float* db   = (const float*)d_in[6];
  const float* Alog = (const float*)d_in[7];
  const float* Dp   = (const float*)d_in[8];
  const float* wo   = (const float*)d_in[9];
  const float* lng  = (const float*)d_in[10];
  const float* lnb  = (const float*)d_in[11];
  const float* wih  = (const float*)d_in[12];
  const float* whh  = (const float*)d_in[13];
  const float* bih  = (const float*)d_in[14];
  const float* bhh  = (const float*)d_in[15];
  const float* fw   = (const float*)d_in[16];
  const float* fb   = (const float*)d_in[17];
  float* out = (float*)d_out;

  float* F = (float*)d_ws;
  float* xz     = F;                       // 4,194,304 f32 (mo at +3,145,728)
  float* mo     = F + 3145728;             // 1,048,576
  __f16* gxh    = (__f16*)(F + 4194304);   // 4,194,304 halves (lstm input proj, f16)
  __f16* u_h    = (__f16*)(F + 6291456);   // 2,097,152 halves
  __f16* xdh    = (__f16*)(F + 7340032);   // 262,144 halves
  float* dt     = F + 7602176;             // 2,097,152 f32 (ends 9,699,328)
  float* mbuf   = F + 10747904;            // 1,048,576
  __f16* fw_h   = (__f16*)(F + 4194304);   // overlaps gxh; packed after lstm done
  __f16* wih_h  = (__f16*)(F + 7602176);   // in dt region (dead until first dt write)
  __f16* wi_hc  = (__f16*)(F + 8388608);   // in dt region, repacked per layer
  float* hend   = F + 8388608;             // aliases wi_hc during scan
  __f16* ybuf_h = (__f16*)(F + 9699328);   // 2,097,152 halves
  __f16* x_h    = (__f16*)(F + 9699328);   // aliases ybuf_h (dead before first scan)
  __f16* mbuf_h = (__f16*)(F + 11796480);  // 1,048,576 halves
  float* Pp     = F + 11796480;            // aliases mbuf_h during scan
  __f16* comb_h = (__f16*)(F + 12320768);  // [m | lf | lb], ld 1024
  __f16* wo_h   = (__f16*)(F + 13369344);  // 1,572,864 halves
  __f16* xpw_h  = (__f16*)(F + 14155776);  // ends 14,352,384
  __f16* dwh    = (__f16*)(F + 14352384);  // ends 14,450,688
  float* c_state = F + 14450688;           // 4096 floats
  uint4* h8_state = (uint4*)(F + 14454784); // 128 uint4 -> ends 14,455,296
  uint4* wpk8   = (uint4*)(F + 14455296);  // 32768 uint4 i8 weights -- OUTSIDE dt
                                           // region (r23 bug: was clobbered by dt)
                                           // ends 14,586,368 floats (~58.3 MB)

  const int M = B_ * L_;                   // 2048
  dim3 blk(256);
  const size_t LSH = 132096;               // dynamic LDS for hosted dispatches

  // one-time packs
  packh<<<dim3(4096), blk, 0, stream>>>(x,   x_h,   1048576);
  packh<<<dim3(4096), blk, 0, stream>>>(wih, wih_h, 1048576);
  packh<<<dim3(6144), blk, 0, stream>>>(wo,  wo_h,  1572864);
  pack_xpw_h<<<dim3(1536), blk, 0, stream>>>(xpw, xpw_h);
  pack_dwh<<<dim3(768), blk, 0, stream>>>(dw, dwh);
  pack_whh_i8<<<dim3(128), blk, 0, stream>>>(whh, wpk8);

  // LSTM input projection -> gxh (f16)
  gemm_mfma_h<0,true><<<dim3(16, 16), blk, 0, stream>>>(
      x_h, wih_h, gxh, M, 2048, 512, 512, 512, 2048, bih, bhh);

  // lstm step budgets: 12 hosted dispatches, 11*43 + 39 = 512
  int scur = 0;
  auto nb = [&](int n) { int a = scur; scur += n; return a; };

  for (int i = 0; i < NL; ++i) {
    const float* min = (i == 0) ? x : mbuf;
    const __f16* min_h = (i == 0) ? x_h : mbuf_h;
    packh<<<dim3(4096), blk, 0, stream>>>(wi + (size_t)i*1048576, wi_hc, 1048576);
    // xz = m @ in_proj^T  (hosted: 128 tile-blocks + 8 lstm)
    { int s0 = nb(43);
      gemm512<0,false><<<dim3(136), dim3(512), LSH, stream>>>(
        min_h, wi_hc, xz, 16, M, 2048, 512, 512, 512, 2048, nullptr,
        128, gxh, wpk8, comb_h, c_state, h8_state, s0, s0 + 43); }
    conv_silu<<<dim3(8192), blk, 0, stream>>>(
        xz, cw + (size_t)i*DIN*DCV, cb + i*DIN, u_h);
    // xdbl (hosted: 8 + 8)
    { int s0 = nb(43);
      gemm512<0,true><<<dim3(16), dim3(512), LSH, stream>>>(
        u_h, xpw_h + (size_t)i*131072, xdh, 1, M, 128, 1024, 1024, 1024, 128, nullptr,
        8, gxh, wpk8, comb_h, c_state, h8_state, s0, s0 + 43); }
    // dt (hosted: 64 + 8)
    { int s0 = nb(43);
      gemm512<1,false><<<dim3(72), dim3(512), LSH, stream>>>(
        xdh, dwh + (size_t)i*65536, dt, 8, M, 1024, 64, 128, 64, 1024, db + i*1024,
        64, gxh, wpk8, comb_h, c_state, h8_state, s0, s0 + 43); }
    scan_part<<<dim3(2048), blk, 0, stream>>>(
        dt, u_h, xdh, Alog + (size_t)i*DIN*DST, hend, Pp);
    scan_fix<<<dim3(2048), blk, 0, stream>>>(
        dt, u_h, xdh, xz, Alog + (size_t)i*DIN*DST, Dp + i*DIN, hend, Pp, ybuf_h);
    // mo (hosted: 32 + 8); last hosted dispatch takes the remaining 39 steps
    { int cnt = (i == NL - 1) ? 39 : 43;
      int s0 = nb(cnt);
      gemm512<0,false><<<dim3(40), dim3(512), LSH, stream>>>(
        ybuf_h, wo_h + (size_t)i*524288, mo, 4, M, 512, 1024, 1024, 1024, 512, nullptr,
        32, gxh, wpk8, comb_h, c_state, h8_state, s0, s0 + cnt); }
    if (i < NL - 1)
      resid_ln<<<dim3(M), dim3(64), 0, stream>>>(
          min, mo, lng + i*512, lnb + i*512, mbuf, 512, mbuf_h, 512);
    else
      resid_ln<<<dim3(M), dim3(64), 0, stream>>>(
          min, mo, lng + i*512, lnb + i*512, nullptr, 0, comb_h, 1024);
  }

  // fusion: out = comb @ fusion_w^T + fb   (gxh dead now; fw_h overlaps it)
  packh<<<dim3(2048), blk, 0, stream>>>(fw, fw_h, 524288);
  gemm_mfma_h<0,false><<<dim3(4, 16), blk, 0, stream>>>(
      comb_h, fw_h, out, M, 512, 1024, 1024, 1024, 512, fb, nullptr);
}

// Round 25
// 1272.939 us; speedup vs baseline: 1.2598x; 1.2598x over previous
//
#include <hip/hip_runtime.h>
#include <math.h>

#define B_  4
#define L_  512
#define D_  512
#define DIN 1024
#define DST 16
#define DCV 4
#define DTR 32
#define NL  3
#define H2  256
#define LCH 64    // scan chunk length (8 chunks)
#define NCH 8
#define WSC 0.28f // lstm i8 weight scale

typedef _Float16 __f16;
typedef __f16 f16x2 __attribute__((ext_vector_type(2)));
typedef __f16 half8 __attribute__((ext_vector_type(8)));
typedef float f32x4v __attribute__((ext_vector_type(4)));
typedef unsigned uint4v __attribute__((ext_vector_type(4)));

__device__ __forceinline__ float fast_sigmoid(float x) { return 1.f / (1.f + __expf(-x)); }
__device__ __forceinline__ float fast_tanh(float x) { return 2.f / (1.f + __expf(-2.f * x)) - 1.f; }

__device__ __forceinline__ unsigned packf16(float a, float b) {
  f16x2 p; p.x = (__f16)a; p.y = (__f16)b;
  return __builtin_bit_cast(unsigned, p);
}
__device__ __forceinline__ int sdot4(unsigned a, unsigned b, int c) {
  return __builtin_amdgcn_sdot4((int)a, (int)b, c, false);
}
__device__ __forceinline__ int q8(float v) {
  float c = fmaxf(fminf(v, 127.f), -127.f);
  return (int)rintf(c);
}

// ---------------- f16-operand MFMA GEMM ----------------
template<int ACT, bool ACC, bool HOUT>
__global__ __launch_bounds__(256) void gemm_mfma_h(
    const __f16* __restrict__ A, const __f16* __restrict__ W, void* __restrict__ Cv,
    int M, int N, int K, int lda, int ldb, int ldc,
    const float* __restrict__ bias, const float* __restrict__ bias2)
{
  __shared__ uint4v As[1024];   // [row][8 kb-slots], phys slot = kb ^ (row&7)
  __shared__ uint4v Bs[1024];
  const int tid  = threadIdx.x;
  const int lane = tid & 63, wid = tid >> 6;
  const int wr = wid >> 1, wc = wid & 1;
  const int fr = lane & 15, fq = lane >> 4;
  const int m0 = blockIdx.y * 128, n0 = blockIdx.x * 128;
  const int srow = tid >> 3, skb = tid & 7;

  f32x4v acc[4][4] = {};
  for (int k0 = 0; k0 < K; k0 += 64) {
    const __f16* Ab = A + (size_t)m0 * lda + k0;
    const __f16* Bb = W + (size_t)n0 * ldb + k0;
    #pragma unroll
    for (int i = 0; i < 4; ++i) {
      int row = srow + i * 32;
      uint4v ap = *(const uint4v*)(Ab + (size_t)row * lda + skb * 8);
      uint4v bp = *(const uint4v*)(Bb + (size_t)row * ldb + skb * 8);
      As[row * 8 + (skb ^ (row & 7))] = ap;
      Bs[row * 8 + (skb ^ (row & 7))] = bp;
    }
    __syncthreads();
    #pragma unroll
    for (int ks = 0; ks < 2; ++ks) {
      half8 af[4], bf[4];
      #pragma unroll
      for (int mt = 0; mt < 4; ++mt) {
        int row = wr * 64 + mt * 16 + fr;
        int kb = ks * 4 + fq;
        af[mt] = __builtin_bit_cast(half8, As[row * 8 + (kb ^ (row & 7))]);
      }
      #pragma unroll
      for (int nt = 0; nt < 4; ++nt) {
        int row = wc * 64 + nt * 16 + fr;
        int kb = ks * 4 + fq;
        bf[nt] = __builtin_bit_cast(half8, Bs[row * 8 + (kb ^ (row & 7))]);
      }
      #pragma unroll
      for (int mt = 0; mt < 4; ++mt)
        #pragma unroll
        for (int nt = 0; nt < 4; ++nt)
          acc[mt][nt] = __builtin_amdgcn_mfma_f32_16x16x32_f16(af[mt], bf[nt], acc[mt][nt], 0, 0, 0);
    }
    __syncthreads();
  }
  float* C = (float*)Cv;
  __f16* Ch = (__f16*)Cv;
  #pragma unroll
  for (int nt = 0; nt < 4; ++nt) {
    int n = n0 + wc * 64 + nt * 16 + fr;
    float bv = (bias ? bias[n] : 0.f) + (bias2 ? bias2[n] : 0.f);
    #pragma unroll
    for (int mt = 0; mt < 4; ++mt) {
      #pragma unroll
      for (int r = 0; r < 4; ++r) {
        int m = m0 + wr * 64 + mt * 16 + fq * 4 + r;
        float v = acc[mt][nt][r] + bv;
        if (ACT == 1) v = (v > 20.f) ? v : log1pf(__expf(v));
        if (HOUT) Ch[(size_t)m * ldc + n] = (__f16)v;
        else if (ACC) C[(size_t)m * ldc + n] += v;
        else C[(size_t)m * ldc + n] = v;
      }
    }
  }
}

// generic f32 -> f16 pack
__global__ __launch_bounds__(256) void packh(
    const float* __restrict__ src, __f16* __restrict__ dst, int n)
{
  int t = blockIdx.x * 256 + threadIdx.x;
  if (t < n) dst[t] = (__f16)src[t];
}

// all 3 layers' x_proj weights, zero-padded 64->128 rows, packed f16
__global__ __launch_bounds__(256) void pack_xpw_h(
    const float* __restrict__ xpw, __f16* __restrict__ dst)
{
  int t = blockIdx.x * 256 + threadIdx.x;   // [0, 3*131072)
  int layer = t >> 17;
  int r = (t >> 10) & 127;
  int k = t & 1023;
  dst[t] = (r < 64) ? (__f16)xpw[layer * 65536 + r * 1024 + k] : (__f16)0.f;
}

// all 3 layers' dt_proj weights, zero-padded K 32->64, packed f16: [layer][1024][64]
__global__ __launch_bounds__(256) void pack_dwh(
    const float* __restrict__ dw, __f16* __restrict__ dst)
{
  int t = blockIdx.x * 256 + threadIdx.x;   // [0, 3*65536)
  int layer = t >> 16;
  int r = (t >> 6) & 1023;
  int k = t & 63;
  dst[t] = (k < 32) ? (__f16)dw[layer * 32768 + r * 32 + k] : (__f16)0.f;
}

// ALL 4 gates -> i8 (fixed scale WSC), layout [dir][G][q][t] uint4, t=(j<<1)|ks
__global__ __launch_bounds__(256) void pack_whh_i8(
    const float* __restrict__ whh, uint4* __restrict__ dst)
{
  int idx = blockIdx.x * 256 + threadIdx.x;   // [0, 32768)
  int t = idx & 511;
  int q = (idx >> 9) & 7;
  int r = idx >> 12;                          // [0, 8)
  int G = r & 3, dir = r >> 2;
  int j = t >> 1, ks = t & 1;
  const float* src = whh + (size_t)dir * 262144 + (size_t)(G * 256 + j) * 256 + ks * 128 + q * 16;
  const float inv = 127.f / WSC;
  unsigned d[4];
  #pragma unroll
  for (int w = 0; w < 4; ++w) {
    float4 f = ((const float4*)src)[w];
    int q0 = q8(f.x * inv), q1 = q8(f.y * inv), q2 = q8(f.z * inv), q3 = q8(f.w * inv);
    d[w] = (unsigned)(q0 & 255) | ((unsigned)(q1 & 255) << 8) |
           ((unsigned)(q2 & 255) << 16) | ((unsigned)(q3 & 255) << 24);
  }
  uint4 pk; pk.x = d[0]; pk.y = d[1]; pk.z = d[2]; pk.w = d[3];
  dst[idx] = pk;
}

// u[b,l,c] = silu(cb[c] + conv(xin)); dual write f32 + f16
__global__ __launch_bounds__(256) void conv_silu(
    const float* __restrict__ xz, const float* __restrict__ cw, const float* __restrict__ cb,
    float* __restrict__ u, __f16* __restrict__ uh)
{
  int t = blockIdx.x * 256 + threadIdx.x;
  int c  = t & (DIN - 1);
  int bl = t >> 10;
  int l  = bl & (L_ - 1);
  float acc = cb[c];
  #pragma unroll
  for (int k = 0; k < DCV; ++k) {
    int ls = l + k - (DCV - 1);
    if (ls >= 0)
      acc = fmaf(xz[(size_t)(bl + k - (DCV - 1)) * 2048 + c], cw[c * DCV + k], acc);
  }
  float v = acc * fast_sigmoid(acc);
  u[t] = v;
  uh[t] = (__f16)v;
}

// ---------------- chunked selective scan (2-pass, exact by linearity) ----------------
__global__ __launch_bounds__(256) void scan_part(
    const float* __restrict__ dt, const float* __restrict__ u,
    const __f16* __restrict__ xdh, const float* __restrict__ A_log,
    float* __restrict__ hend, float* __restrict__ Pp)
{
  int t = blockIdx.x * 256 + threadIdx.x;   // [0, 524288)
  int n  = t & 15;
  int ch = (t >> 4) & 7;
  int bc = t >> 7;
  int c  = bc & (DIN - 1);
  int b  = bc >> 10;
  float Ac = -__expf(A_log[c * DST + n]);
  float h = 0.f, P = 1.f;
  const size_t row = (size_t)b * L_ + ch * LCH;

#define DECLP(i) float dtv##i, uv##i, Bn##i;
  DECLP(0) DECLP(1) DECLP(2) DECLP(3)
#define LOADP(i, l) { \
    const size_t nb_ = row + (l); \
    dtv##i = dt[nb_ * DIN + c]; \
    uv##i  = u [nb_ * DIN + c]; \
    Bn##i  = (float)xdh[nb_ * 128 + 32 + n]; }
#define STEPP(i) { \
    float dA_ = __expf(dtv##i * Ac); \
    h = fmaf(dA_, h, (dtv##i * uv##i) * Bn##i); \
    P *= dA_; }

  LOADP(0, 0) LOADP(1, 1) LOADP(2, 2) LOADP(3, 3)
  for (int l = 0; l < LCH - 4; l += 4) {
    STEPP(0) LOADP(0, l + 4)
    STEPP(1) LOADP(1, l + 5)
    STEPP(2) LOADP(2, l + 6)
    STEPP(3) LOADP(3, l + 7)
  }
  STEPP(0) STEPP(1) STEPP(2) STEPP(3)
#undef DECLP
#undef LOADP
#undef STEPP
  int flat = bc * 16 + n;
  hend[ch * 65536 + flat] = h;
  Pp[ch * 65536 + flat]   = P;
}

__global__ __launch_bounds__(256) void scan_fix(
    const float* __restrict__ dt, const float* __restrict__ u,
    const __f16* __restrict__ xdh, const float* __restrict__ xz,
    const float* __restrict__ A_log, const float* __restrict__ Dp,
    const float* __restrict__ hend, const float* __restrict__ Pp,
    __f16* __restrict__ y)
{
  int t = blockIdx.x * 256 + threadIdx.x;   // [0, 524288)
  int n  = t & 15;
  int ch = (t >> 4) & 7;
  int bc = t >> 7;
  int c  = bc & (DIN - 1);
  int b  = bc >> 10;
  float Ac = -__expf(A_log[c * DST + n]);
  float Dc = Dp[c];
  const int flat = bc * 16 + n;
  float h = 0.f;
  for (int c2 = 0; c2 < ch; ++c2)
    h = fmaf(Pp[c2 * 65536 + flat], h, hend[c2 * 65536 + flat]);
  const size_t row = (size_t)b * L_ + ch * LCH;

#define DECLP(i) float dtv##i, uv##i, Bn##i, Cn##i, zv##i;
  DECLP(0) DECLP(1) DECLP(2) DECLP(3)
#define LOADP(i, l) { \
    const size_t nb_ = row + (l); \
    dtv##i = dt[nb_ * DIN + c]; \
    uv##i  = u [nb_ * DIN + c]; \
    Bn##i  = (float)xdh[nb_ * 128 + 32 + n]; \
    Cn##i  = (float)xdh[nb_ * 128 + 48 + n]; \
    zv##i  = xz[nb_ * 2048 + 1024 + c]; }
#define STEPP(i, l) { \
    float dA_ = __expf(dtv##i * Ac); \
    h = fmaf(dA_, h, (dtv##i * uv##i) * Bn##i); \
    float p_ = h * Cn##i; \
    p_ += __shfl_xor(p_, 1, 64); \
    p_ += __shfl_xor(p_, 2, 64); \
    p_ += __shfl_xor(p_, 4, 64); \
    p_ += __shfl_xor(p_, 8, 64); \
    if (n == 0) { \
      float yv_ = p_ + uv##i * Dc; \
      yv_ *= zv##i * fast_sigmoid(zv##i); \
      y[(row + (l)) * DIN + c] = (__f16)yv_; \
    } }

  LOADP(0, 0) LOADP(1, 1) LOADP(2, 2) LOADP(3, 3)
  for (int l = 0; l < LCH - 4; l += 4) {
    STEPP(0, l)     LOADP(0, l + 4)
    STEPP(1, l + 1) LOADP(1, l + 5)
    STEPP(2, l + 2) LOADP(2, l + 6)
    STEPP(3, l + 3) LOADP(3, l + 7)
  }
  STEPP(0, LCH - 4) STEPP(1, LCH - 3) STEPP(2, LCH - 2) STEPP(3, LCH - 1)
#undef DECLP
#undef LOADP
#undef STEPP
}

// layernorm(a + mo)*g + b -> optional f32 out + f16 out
__global__ __launch_bounds__(64) void resid_ln(
    const float* __restrict__ a, const float* __restrict__ mo,
    const float* __restrict__ g, const float* __restrict__ bta,
    float* __restrict__ outm, int ldo, __f16* __restrict__ outh, int ldoh)
{
  int row = blockIdx.x;
  int lane = threadIdx.x;
  const float* pa = a  + (size_t)row * 512;
  const float* pb = mo + (size_t)row * 512;
  float v[8];
  float s = 0.f, s2 = 0.f;
  #pragma unroll
  for (int i = 0; i < 8; ++i) {
    float x = pa[lane + i * 64] + pb[lane + i * 64];
    v[i] = x; s += x; s2 += x * x;
  }
  #pragma unroll
  for (int off = 1; off < 64; off <<= 1) {
    s  += __shfl_xor(s,  off, 64);
    s2 += __shfl_xor(s2, off, 64);
  }
  float mean = s * (1.f / 512.f);
  float var  = s2 * (1.f / 512.f) - mean * mean;
  float rstd = rsqrtf(var + 1e-5f);
  #pragma unroll
  for (int i = 0; i < 8; ++i) {
    int cidx = lane + i * 64;
    float o = (v[i] - mean) * rstd * g[cidx] + bta[cidx];
    if (outm) outm[(size_t)row * ldo + cidx] = o;
    outh[(size_t)row * ldoh + cidx] = (__f16)o;
  }
}

// ---------------- LSTM recurrence: ALL gates i8; i,f from L2, g+o from LDS ----------------
// Block per (dir,b), 512 thr = (unit j=t>>1) x (K-half ks=t&1).
// Empirical optimum of 13 structural variants (r5-r24): 633us. Step time is
// ~50% fixed dependency chain (barrier/LDS/shfl/transcendental) + L2/LDS streams.
// Piggybacking on GEMM dispatches (r23/r24) regressed: L2 contention with
// concurrent GEMM traffic inflated per-step cost 1.24 -> 2.5 us.

#define W8STEP(q) { \
    uint4 hq = h8s[buf][(q)*2 + ks]; \
    uint4 wi_ = wp8[(0*8+(q))*512 + t]; \
    uint4 wf_ = wp8[(1*8+(q))*512 + t]; \
    uint4 wg = wg_lds[(q)*512 + t]; \
    uint4 wo = wo_lds[(q)*512 + t]; \
    ii_ = sdot4(wi_.x, hq.x, ii_); ii_ = sdot4(wi_.y, hq.y, ii_); \
    ii_ = sdot4(wi_.z, hq.z, ii_); ii_ = sdot4(wi_.w, hq.w, ii_); \
    if_ = sdot4(wf_.x, hq.x, if_); if_ = sdot4(wf_.y, hq.y, if_); \
    if_ = sdot4(wf_.z, hq.z, if_); if_ = sdot4(wf_.w, hq.w, if_); \
    ig_ = sdot4(wg.x, hq.x, ig_); ig_ = sdot4(wg.y, hq.y, ig_); \
    ig_ = sdot4(wg.z, hq.z, ig_); ig_ = sdot4(wg.w, hq.w, ig_); \
    io_ = sdot4(wo.x, hq.x, io_); io_ = sdot4(wo.y, hq.y, io_); \
    io_ = sdot4(wo.z, hq.z, io_); io_ = sdot4(wo.w, hq.w, io_); }
#define REP8(M) M(0) M(1) M(2) M(3) M(4) M(5) M(6) M(7)

__global__ __launch_bounds__(512, 1) void lstm_rec(
    const float* __restrict__ gx, const uint4* __restrict__ wpk8,
    __f16* __restrict__ comb)
{
  __shared__ uint4 wg_lds[8 * 512];             // 64KB g-gate i8
  __shared__ uint4 wo_lds[8 * 512];             // 64KB o-gate i8
  __shared__ __align__(16) uint4 h8s[2][16];    // i8 h quads, [buf][q*2+ks]
  const int dir = blockIdx.x >> 2, b = blockIdx.x & 3;
  const int t = threadIdx.x;
  const int j = t >> 1, ks = t & 1;
  const uint4* wp8 = wpk8 + (size_t)dir * 4 * 8 * 512;
  const float WS = WSC / (127.f * 127.f);

  #pragma unroll
  for (int q = 0; q < 8; ++q) {
    wg_lds[q * 512 + t] = wp8[(2 * 8 + q) * 512 + t];
    wo_lds[q * 512 + t] = wp8[(3 * 8 + q) * 512 + t];
  }

  if (t < 128) ((unsigned*)h8s)[t] = 0u;
  float c_reg = 0.f;
  __f16* outp = comb + 512 + dir * 256;
  const float* gxb = gx + (size_t)(b * L_) * 2048 + dir * 1024;
  const int offA = (ks ? 1 : 0) * 256 + j;   // ks0 -> gate i, ks1 -> gate f
  const int offB = (ks ? 3 : 2) * 256 + j;   // ks0 -> gate g, ks1 -> gate o
  const int d_   = t >> 3;
  const int ks8  = d_ >> 5;
  const int h8i  = (((d_ - ks8 * 32) >> 2) * 2 + ks8) * 4 + (d_ & 3);
  __syncthreads();

  int buf = 0;
  const int l0 = dir ? (L_ - 1) : 0;
  float pgA = gxb[(size_t)l0 * 2048 + offA];
  float pgB = gxb[(size_t)l0 * 2048 + offB];

  for (int s = 0; s < L_; ++s) {
    const int l = dir ? (L_ - 1 - s) : s;
    float pgA_n = 0.f, pgB_n = 0.f;
    if (s + 1 < L_) {
      const int ln = dir ? (L_ - 2 - s) : (s + 1);
      pgA_n = gxb[(size_t)ln * 2048 + offA];
      pgB_n = gxb[(size_t)ln * 2048 + offB];
    }
    int ii_ = 0, if_ = 0, ig_ = 0, io_ = 0;
    REP8(W8STEP)
    float a0 = (float)ii_ * WS;
    float a1 = (float)if_ * WS;
    float a2 = (float)ig_ * WS;
    float a3 = (float)io_ * WS;
    if (ks == 0) { a0 += pgA; a2 += pgB; } else { a1 += pgA; a3 += pgB; }
    a0 += __shfl_xor(a0, 1, 64);
    a1 += __shfl_xor(a1, 1, 64);
    a2 += __shfl_xor(a2, 1, 64);
    a3 += __shfl_xor(a3, 1, 64);
    const float si = fast_sigmoid(a0);
    const float sf = fast_sigmoid(a1);
    const float tg = fast_tanh(a2);
    const float so = fast_sigmoid(a3);
    c_reg = fmaf(sf, c_reg, si * tg);
    const float hv = so * fast_tanh(c_reg);
    if (ks == 0) outp[(size_t)(b * L_ + l) * 1024 + j] = (__f16)hv;
    const float hv1 = __shfl_xor(hv, 2, 64);    // h[j+1] (j even)
    const float hv2 = __shfl_xor(hv, 4, 64);    // h[j+2] (j%4==0)
    const float hv3 = __shfl_xor(hv1, 4, 64);   // h[j+3] (j%4==0)
    if ((t & 7) == 0) {
      int q0 = (int)rintf(hv  * 127.f), q1 = (int)rintf(hv1 * 127.f);
      int q2 = (int)rintf(hv2 * 127.f), q3 = (int)rintf(hv3 * 127.f);
      ((unsigned*)h8s[buf ^ 1])[h8i] =
          (unsigned)(q0 & 255) | ((unsigned)(q1 & 255) << 8) |
          ((unsigned)(q2 & 255) << 16) | ((unsigned)(q3 & 255) << 24);
    }
    pgA = pgA_n; pgB = pgB_n;
    buf ^= 1;
    __syncthreads();
  }
}

extern "C" void kernel_launch(void* const* d_in, const int* in_sizes, int n_in,
                              void* d_out, int out_size, void* d_ws, size_t ws_size,
                              hipStream_t stream)
{
  const float* x    = (const float*)d_in[0];
  const float* wi   = (const float*)d_in[1];
  const float* cw   = (const float*)d_in[2];
  const float* cb   = (const float*)d_in[3];
  const float* xpw  = (const float*)d_in[4];
  const float* dw   = (const float*)d_in[5];
  const float* db   = (const float*)d_in[6];
  const float* Alog = (const float*)d_in[7];
  const float* Dp   = (const float*)d_in[8];
  const float* wo   = (const float*)d_in[9];
  const float* lng  = (const float*)d_in[10];
  const float* lnb  = (const float*)d_in[11];
  const float* wih  = (const float*)d_in[12];
  const float* whh  = (const float*)d_in[13];
  const float* bih  = (const float*)d_in[14];
  const float* bhh  = (const float*)d_in[15];
  const float* fw   = (const float*)d_in[16];
  const float* fb   = (const float*)d_in[17];
  float* out = (float*)d_out;

  float* F = (float*)d_ws;
  // f32 buffers
  float* xz     = F;                       // 4,194,304 (gx aliases; mo at +3,145,728)
  float* gx     = F;
  float* mo     = F + 3145728;             // 1,048,576
  float* u      = F + 4194304;             // 2,097,152
  __f16* xdh    = (__f16*)(F + 7340032);   // 262,144 halves (xdbl f16, ld 128)
  float* dt     = F + 7602176;             // 2,097,152 (ends 9,699,328)
  float* mbuf   = F + 10747904;            // 1,048,576
  // f16 / packed buffers (aliased into dead windows)
  __f16* fw_h   = (__f16*)(F + 4194304);   // in u region, packed after last u use
  __f16* u_h    = (__f16*)(F + 6291456);   // 2,097,152 halves
  __f16* wih_h  = (__f16*)(F + 7602176);   // in dt region (dead until first dt write)
  uint4* wpk8   = (uint4*)(F + 8126464);   // 32768 uint4 i8, all 4 gates (ends 8,257,536)
  __f16* wi_hc  = (__f16*)(F + 8388608);   // in dt region, repacked per layer (1M halves)
  float* hend   = F + 8388608;             // aliases wi_hc region during scan (524,288)
  __f16* ybuf_h = (__f16*)(F + 9699328);   // 2,097,152 halves
  __f16* x_h    = (__f16*)(F + 9699328);   // aliases ybuf_h (dead before first scan)
  __f16* mbuf_h = (__f16*)(F + 11796480);  // 1,048,576 halves
  float* Pp     = F + 11796480;            // aliases mbuf_h region during scan (524,288)
  __f16* comb_h = (__f16*)(F + 12320768);  // 2,097,152 halves [m | lf | lb], ld 1024
  __f16* wo_h   = (__f16*)(F + 13369344);  // 1,572,864 halves
  __f16* xpw_h  = (__f16*)(F + 14155776);  //   393,216 halves -> ends 14,352,384
  __f16* dwh    = (__f16*)(F + 14352384);  //   196,608 halves -> ends 14,450,688

  const int M = B_ * L_;                   // 2048
  dim3 blk(256);

  // one-time packs
  packh<<<dim3(4096), blk, 0, stream>>>(x,   x_h,   1048576);
  packh<<<dim3(4096), blk, 0, stream>>>(wih, wih_h, 1048576);
  packh<<<dim3(6144), blk, 0, stream>>>(wo,  wo_h,  1572864);
  pack_xpw_h<<<dim3(1536), blk, 0, stream>>>(xpw, xpw_h);
  pack_dwh<<<dim3(768), blk, 0, stream>>>(dw, dwh);

  // LSTM input projection + recurrence
  gemm_mfma_h<0,false,false><<<dim3(16, 16), blk, 0, stream>>>(
      x_h, wih_h, gx, M, 2048, 512, 512, 512, 2048, bih, bhh);
  pack_whh_i8<<<dim3(128), blk, 0, stream>>>(whh, wpk8);
  lstm_rec<<<dim3(8), dim3(512), 0, stream>>>(gx, wpk8, comb_h);

  for (int i = 0; i < NL; ++i) {
    const float* min = (i == 0) ? x : mbuf;
    const __f16* min_h = (i == 0) ? x_h : mbuf_h;
    packh<<<dim3(4096), blk, 0, stream>>>(wi + (size_t)i*1048576, wi_hc, 1048576);
    // xz = m @ in_proj^T
    gemm_mfma_h<0,false,false><<<dim3(16, 16), blk, 0, stream>>>(
        min_h, wi_hc, xz, M, 2048, 512, 512, 512, 2048, nullptr, nullptr);
    // u = silu(conv(xin)+cb)  (f32 + f16)
    conv_silu<<<dim3(8192), blk, 0, stream>>>(
        xz, cw + (size_t)i*DIN*DCV, cb + i*DIN, u, u_h);
    // xdbl = u @ xpw_pad^T  (f16 out, ld 128)
    gemm_mfma_h<0,false,true><<<dim3(1, 16), blk, 0, stream>>>(
        u_h, xpw_h + (size_t)i*131072, xdh, M, 128, 1024, 1024, 1024, 128, nullptr, nullptr);
    // dt = softplus(dt_in @ dt_proj^T + db)  (MFMA, K padded 32->64)
    gemm_mfma_h<1,false,false><<<dim3(8, 16), blk, 0, stream>>>(
        xdh, dwh + (size_t)i*65536, dt, M, 1024, 64, 128, 64, 1024, db + i*1024, nullptr);
    // chunked scan: pass A (8 chunk summaries) + pass B (fold & emit y)
    scan_part<<<dim3(2048), blk, 0, stream>>>(
        dt, u, xdh, Alog + (size_t)i*DIN*DST, hend, Pp);
    scan_fix<<<dim3(2048), blk, 0, stream>>>(
        dt, u, xdh, xz, Alog + (size_t)i*DIN*DST, Dp + i*DIN, hend, Pp, ybuf_h);
    // mo = y @ out_proj^T
    gemm_mfma_h<0,false,false><<<dim3(4, 16), blk, 0, stream>>>(
        ybuf_h, wo_h + (size_t)i*524288, mo, M, 512, 1024, 1024, 1024, 512, nullptr, nullptr);
    // m = LN(m + mo): layers 0,1 -> mbuf(+h); layer 2 -> comb cols [0,512)
    if (i < NL - 1)
      resid_ln<<<dim3(M), dim3(64), 0, stream>>>(
          min, mo, lng + i*512, lnb + i*512, mbuf, 512, mbuf_h, 512);
    else
      resid_ln<<<dim3(M), dim3(64), 0, stream>>>(
          min, mo, lng + i*512, lnb + i*512, nullptr, 0, comb_h, 1024);
  }

  // fusion: out = comb @ fusion_w^T + fb
  packh<<<dim3(2048), blk, 0, stream>>>(fw, fw_h, 524288);
  gemm_mfma_h<0,false,false><<<dim3(4, 16), blk, 0, stream>>>(
      comb_h, fw_h, out, M, 512, 1024, 1024, 1024, 512, fb, nullptr);
}